// Round 6
// baseline (1148.727 us; speedup 1.0000x reference)
//
#include <hip/hip_runtime.h>
#include <hip/hip_bf16.h>
#include <cstdint>

typedef __attribute__((ext_vector_type(8))) short short8;
typedef __attribute__((ext_vector_type(4))) float f32x4;

#define NS 512
#define NB 32
#define NE 768
#define NH 128
#define NT 15
#define NM (NB*NS)      // 16384 rows, m = b*512 + s

__device__ __forceinline__ float bflo(unsigned int u){ return __builtin_bit_cast(float, u << 16); }
__device__ __forceinline__ float bfhi(unsigned int u){ return __builtin_bit_cast(float, u & 0xffff0000u); }
__device__ __forceinline__ float sigf(float x){ return __fdividef(1.f, 1.f + __expf(-x)); }
__device__ __forceinline__ float tanhf_(float x){ return 1.f - __fdividef(2.f, __expf(2.f*x) + 1.f); }

__device__ __forceinline__ void gload16(const void* g, void* l) {
#if __has_builtin(__builtin_amdgcn_global_load_lds)
  __builtin_amdgcn_global_load_lds((const __attribute__((address_space(1))) void*)g,
                                   (__attribute__((address_space(3))) void*)l, 16, 0, 0);
#else
  *(uint4*)l = *(const uint4*)g;
#endif
}

// ---------------- converts ----------------
__global__ void cvt_bf16_kernel(const float* __restrict__ in,
                                __hip_bfloat16* __restrict__ out, int n4) {
  int i = blockIdx.x*blockDim.x + threadIdx.x;
  int stride = gridDim.x*blockDim.x;
  for (int j = i; j < n4; j += stride) {
    float4 v = ((const float4*)in)[j];
    ushort4 o;
    o.x = __builtin_bit_cast(unsigned short, __float2bfloat16(v.x));
    o.y = __builtin_bit_cast(unsigned short, __float2bfloat16(v.y));
    o.z = __builtin_bit_cast(unsigned short, __float2bfloat16(v.z));
    o.w = __builtin_bit_cast(unsigned short, __float2bfloat16(v.w));
    ((ushort4*)out)[j] = o;
  }
}

// permuted row n = dir*512 + (j*4+g)  <- src row (g*128+j) of dir's weight
__global__ void cvt_wih_perm(const float* __restrict__ wf, const float* __restrict__ wb,
                             __hip_bfloat16* __restrict__ out) {
  const int n = blockIdx.x;           // 0..1023
  const int dir = n >> 9, cc = n & 511, j = cc >> 2, g = cc & 3;
  const float* src = (dir ? wb : wf) + (size_t)(g*128 + j)*768;
  __hip_bfloat16* dst = out + (size_t)n*768;
  for (int e = threadIdx.x; e < 768; e += 256) dst[e] = __float2bfloat16(src[e]);
}

__global__ void cvt_whh_perm(const float* __restrict__ wf, const float* __restrict__ wb,
                             __hip_bfloat16* __restrict__ out) {
  const int n = blockIdx.x;           // 0..1023 = dir*512+cc
  const int dir = n >> 9, cc = n & 511, j = cc >> 2, g = cc & 3;
  const float* src = (dir ? wb : wf) + (size_t)(g*128 + j)*128;
  __hip_bfloat16* dst = out + (size_t)n*128;
  if (threadIdx.x < 128) dst[threadIdx.x] = __float2bfloat16(src[threadIdx.x]);
}

__global__ void bias_perm_kernel(const float* __restrict__ bihf, const float* __restrict__ bhhf,
                                 const float* __restrict__ bihb, const float* __restrict__ bhhb,
                                 float* __restrict__ biasp) {
  const int n = blockIdx.x*blockDim.x + threadIdx.x;
  if (n >= 1024) return;
  const int dir = n >> 9, cc = n & 511, j = cc >> 2, g = cc & 3;
  const int src = g*128 + j;
  biasp[n] = dir ? (bihb[src] + bhhb[src]) : (bihf[src] + bhhf[src]);
}

// ---------------- xproj GEMM: A[16384x768] @ Bw[1024x768]^T -> xqd[2][NM][512] ----------------
__global__ __launch_bounds__(256, 2) void gemm_xproj(
    const __hip_bfloat16* __restrict__ A,
    const __hip_bfloat16* __restrict__ Bw,
    const float* __restrict__ biasp,
    __hip_bfloat16* __restrict__ xqd)        // [2][NM][512]
{
  __shared__ __align__(16) __hip_bfloat16 As[128*64];
  __shared__ __align__(16) __hip_bfloat16 Bs[128*64];
  const int bm = blockIdx.x * 128;
  const int bn = blockIdx.y * 128;
  const int tid = threadIdx.x;
  const int lane = tid & 63;
  const int wv = tid >> 6;
  const int wr = wv >> 1, wc = wv & 1;
  char* AsB = (char*)As;
  char* BsB = (char*)Bs;
  const char* Ab = (const char*)A;
  const char* Bb = (const char*)Bw;
  f32x4 acc[4][4] = {};

  for (int kt = 0; kt < 12; ++kt) {
    const int k0 = kt * 64;
    __syncthreads();
    #pragma unroll
    for (int i = 0; i < 4; ++i) {
      int fb = i*4096 + tid*16;
      int r  = fb >> 7;
      int cb = fb & 127;
      gload16(Ab + ((size_t)(bm + r)*768 + k0)*2 + cb, AsB + fb);
      gload16(Bb + ((size_t)(bn + r)*768 + k0)*2 + cb, BsB + fb);
    }
    __syncthreads();
    #pragma unroll
    for (int ks = 0; ks < 2; ++ks) {
      const int krow = ks*32 + ((lane >> 4) << 3);
      short8 af[4], bfr[4];
      #pragma unroll
      for (int m = 0; m < 4; ++m) {
        int row = wr*64 + m*16 + (lane & 15);
        af[m] = *(const short8*)(AsB + (row*64 + krow)*2);
      }
      #pragma unroll
      for (int n = 0; n < 4; ++n) {
        int row = wc*64 + n*16 + (lane & 15);
        bfr[n] = *(const short8*)(BsB + (row*64 + krow)*2);
      }
      #pragma unroll
      for (int m = 0; m < 4; ++m)
        #pragma unroll
        for (int n = 0; n < 4; ++n)
          acc[m][n] = __builtin_amdgcn_mfma_f32_16x16x32_bf16(af[m], bfr[n], acc[m][n], 0, 0, 0);
    }
  }
  #pragma unroll
  for (int m = 0; m < 4; ++m) {
    #pragma unroll
    for (int n = 0; n < 4; ++n) {
      const int col = bn + wc*64 + n*16 + (lane & 15);
      const float bv = biasp[col];
      const int dir = col >> 9;
      const int cc  = col & 511;
      #pragma unroll
      for (int jj = 0; jj < 4; ++jj) {
        const int row = bm + wr*64 + m*16 + ((lane >> 4)*4 + jj);
        xqd[((size_t)dir*NM + row)*512 + cc] = __float2bfloat16(acc[m][n][jj] + bv);
      }
    }
  }
}

// ---------------- LSTM recurrence via MFMA, in-lane activation, 1 barrier/step ----------------
// 16 blocks = (dir, bg), 4 batches each, 512 threads = 8 waves.
// row encoding j*4+gate means lane (ln,lp) of wave w, tile r holds ALL 4 gates of
// h-index j=(w*4+r)*4+lp for batch ln in acc[r]. Lanes ln<4 run the activation
// in place; C-in is initialized from packed xq (z+x fused into the MFMA).
// h goes back to LDS B-fragment layout (dbuf) with 4 ds_write_b16; ONE barrier/step.
__global__ __launch_bounds__(512) __attribute__((amdgpu_waves_per_eu(2, 2)))
void lstm_mfma(
    const __hip_bfloat16* __restrict__ xqd,   // [2][NM][512] packed j*4+g, bias folded
    const __hip_bfloat16* __restrict__ whhp,  // [2][512][128] permuted rows
    float* __restrict__ hf,                   // [NM][128]
    float* __restrict__ hb)                   // [NM][128]
{
  __shared__ __align__(16) char hfrag[2*4224];   // [buf][kc:1056B][lane:16B] B-frag layout

  const int bid = blockIdx.x;
  const int dir = bid >> 3, bg = bid & 7;
  const int t = threadIdx.x;
  const int w = t >> 6, l = t & 63;
  const int ln = l & 15, lp = l >> 4;
  const bool prod = (ln < 4);

  // A-fragments: wave w rows (w*4+r)*16+ln, k = kc*32 + lp*8 + e. 64 dwords/lane.
  uint4 afu[4][4];
  {
    const char* wbase = (const char*)(whhp + (size_t)dir*512*128);
    #pragma unroll
    for (int r = 0; r < 4; ++r) {
      const int row = (w*4 + r)*16 + ln;
      #pragma unroll
      for (int kc = 0; kc < 4; ++kc)
        afu[r][kc] = *(const uint4*)(wbase + ((size_t)row*128 + lp*8 + kc*32)*2);
    }
  }
  // opaque pin once: asm-defined values must stay materialized (VGPR or AGPR —
  // MFMA reads either directly).
  #pragma unroll
  for (int r = 0; r < 4; ++r)
    #pragma unroll
    for (int kc = 0; kc < 4; ++kc)
      asm volatile("" : "+v"(afu[r][kc].x), "+v"(afu[r][kc].y),
                        "+v"(afu[r][kc].z), "+v"(afu[r][kc].w));

  for (int i = t; i < 2*4224/4; i += 512) ((int*)hfrag)[i] = 0;

  // producer identity (lanes ln<4): batch b=ln, h-indices jr[r]=(w*4+r)*4+lp
  const int bsafe = bg*4 + (ln & 3);
  int jr[4], woff[4];
  #pragma unroll
  for (int r = 0; r < 4; ++r) {
    jr[r] = (w*4 + r)*4 + lp;
    woff[r] = (jr[r] >> 5)*1056 + (((jr[r] >> 3) & 3)*16 + (ln & 3))*16 + (jr[r] & 7)*2;
  }
  const __hip_bfloat16* xb = xqd + ((size_t)dir*NM + (size_t)bsafe*512)*512;
  float* hout = (dir ? hb : hf) + (size_t)bsafe*512*128;

  float cst[4] = {0.f, 0.f, 0.f, 0.f};
  uint2 xc[4], xn[4];
  if (prod) {
    const int s0 = dir ? 511 : 0, s1 = dir ? 510 : 1;
    #pragma unroll
    for (int r = 0; r < 4; ++r) {
      xc[r] = *(const uint2*)(xb + (size_t)s0*512 + jr[r]*4);
      xn[r] = *(const uint2*)(xb + (size_t)s1*512 + jr[r]*4);
    }
  }
  __syncthreads();   // prologue only

  int buf = 0;
  for (int si = 0; si < 512; ++si) {
    const int s = dir ? (511 - si) : si;

    // B-fragments: lane-linear, conflict-free
    short8 bfv[4];
    #pragma unroll
    for (int kc = 0; kc < 4; ++kc)
      bfv[kc] = *(const short8*)(hfrag + buf*4224 + kc*1056 + l*16);

    // C-in = packed x (z+x fused); zero on non-producer lanes
    f32x4 acc[4];
    #pragma unroll
    for (int r = 0; r < 4; ++r) {
      if (prod) acc[r] = f32x4{bflo(xc[r].x), bfhi(xc[r].x), bflo(xc[r].y), bfhi(xc[r].y)};
      else      acc[r] = f32x4{0.f, 0.f, 0.f, 0.f};
      #pragma unroll
      for (int kc = 0; kc < 4; ++kc)
        acc[r] = __builtin_amdgcn_mfma_f32_16x16x32_bf16(
                   __builtin_bit_cast(short8, afu[r][kc]), bfv[kc], acc[r], 0, 0, 0);
    }

    // x prefetch for si+2 (in flight across the barrier)
    uint2 x2[4] = {xn[0], xn[1], xn[2], xn[3]};
    if (prod && si + 2 < 512) {
      const int sn = dir ? (509 - si) : (si + 2);
      #pragma unroll
      for (int r = 0; r < 4; ++r)
        x2[r] = *(const uint2*)(xb + (size_t)sn*512 + jr[r]*4);
    }

    // in-lane activation + h writes (producer lanes only)
    if (prod) {
      #pragma unroll
      for (int r = 0; r < 4; ++r) {
        const float zi = acc[r][0], zf = acc[r][1], zg = acc[r][2], zo = acc[r][3];
        cst[r] = sigf(zf)*cst[r] + sigf(zi)*tanhf_(zg);
        const float h = sigf(zo)*tanhf_(cst[r]);
        *(short*)(hfrag + (buf ^ 1)*4224 + woff[r]) =
            (short)__builtin_bit_cast(unsigned short, __float2bfloat16(h));
        hout[(size_t)s*128 + jr[r]] = h;
      }
    }
    #pragma unroll
    for (int r = 0; r < 4; ++r) { xc[r] = xn[r]; xn[r] = x2[r]; }

    asm volatile("s_waitcnt lgkmcnt(0)" ::: "memory");
    __builtin_amdgcn_s_barrier();
    __builtin_amdgcn_sched_barrier(0);
    buf ^= 1;
  }
}

// ---------------- emissions: em[m][t] = [hf|hb][m] . Wp[t] + bp[t] ----------------
__global__ __launch_bounds__(256) void em_kernel(
    const float* __restrict__ hf, const float* __restrict__ hb,
    const float* __restrict__ Wp, const float* __restrict__ bp,
    float* __restrict__ em)
{
  __shared__ float wps[15*256];
  __shared__ float bps[15];
  const int tid = threadIdx.x;
  for (int i = tid; i < 15*256; i += 256) wps[i] = Wp[i];
  if (tid < 15) bps[tid] = bp[tid];
  __syncthreads();
  const size_t m = (size_t)blockIdx.x*256 + tid;
  float acc[15];
  #pragma unroll
  for (int t2 = 0; t2 < 15; ++t2) acc[t2] = bps[t2];
  const float4* hf4 = (const float4*)(hf + m*128);
  const float4* hb4 = (const float4*)(hb + m*128);
  for (int kc = 0; kc < 32; ++kc) {
    float4 hv = hf4[kc];
    #pragma unroll
    for (int t2 = 0; t2 < 15; ++t2)
      acc[t2] += hv.x*wps[t2*256 + kc*4+0] + hv.y*wps[t2*256 + kc*4+1]
               + hv.z*wps[t2*256 + kc*4+2] + hv.w*wps[t2*256 + kc*4+3];
  }
  for (int kc = 0; kc < 32; ++kc) {
    float4 hv = hb4[kc];
    #pragma unroll
    for (int t2 = 0; t2 < 15; ++t2)
      acc[t2] += hv.x*wps[t2*256 + 128 + kc*4+0] + hv.y*wps[t2*256 + 128 + kc*4+1]
               + hv.z*wps[t2*256 + 128 + kc*4+2] + hv.w*wps[t2*256 + 128 + kc*4+3];
  }
  float* eo = em + m*15;
  #pragma unroll
  for (int t2 = 0; t2 < 15; ++t2) eo[t2] = acc[t2];
}

// ---------------- CRF NLL: one block (1 wave) per batch -> partial per b ----------------
__global__ __launch_bounds__(64) void crf_kernel(
    const float* __restrict__ em,
    const int* __restrict__ tags, const int* __restrict__ mask,
    const float* __restrict__ trans, const float* __restrict__ start_t,
    const float* __restrict__ end_t, float* __restrict__ nllb)
{
  __shared__ __align__(16) float ems[512*15];
  __shared__ float trs[225];
  __shared__ int tgs[512];
  __shared__ int mks[512];
  const int b = blockIdx.x, j = threadIdx.x;
  const float* emb = em + (size_t)b*512*15;
  {
    const float4* s4 = (const float4*)emb;
    float4* d4 = (float4*)ems;
    for (int i = j; i < 512*15/4; i += 64) d4[i] = s4[i];
    for (int i = j; i < 512; i += 64) { tgs[i] = tags[b*512+i]; mks[i] = mask[b*512+i]; }
    for (int i = j; i < 225; i += 64) trs[i] = trans[i];
  }
  __syncthreads();

  float trc[15];
  #pragma unroll
  for (int i = 0; i < 15; ++i) trc[i] = (j < 15) ? trs[i*15 + j] : 0.f;

  float alpha = (j < 15) ? (start_t[j] + ems[j]) : -3.0e38f;
  for (int s = 1; s < 512; ++s) {
    const float emv = (j < 15) ? ems[s*15 + j] : 0.f;
    const int msk = mks[s];
    float v[15];
    #pragma unroll
    for (int i = 0; i < 15; ++i) {
      const float ai = __shfl(alpha, i, 64);
      v[i] = ai + trc[i];
    }
    const float t01 = fmaxf(v[0], v[1]),  t23 = fmaxf(v[2], v[3]);
    const float t45 = fmaxf(v[4], v[5]),  t67 = fmaxf(v[6], v[7]);
    const float t89 = fmaxf(v[8], v[9]),  tab = fmaxf(v[10], v[11]);
    const float tcd = fmaxf(v[12], v[13]);
    const float q0 = fmaxf(t01, t23), q1 = fmaxf(t45, t67);
    const float q2 = fmaxf(t89, tab), q3 = fmaxf(tcd, v[14]);
    const float mx = fmaxf(fmaxf(q0, q1), fmaxf(q2, q3));
    float e[15];
    #pragma unroll
    for (int i = 0; i < 15; ++i) e[i] = __expf(v[i] - mx);
    const float s01 = e[0]+e[1], s23 = e[2]+e[3], s45 = e[4]+e[5], s67 = e[6]+e[7];
    const float s89 = e[8]+e[9], sab = e[10]+e[11], scd = e[12]+e[13];
    const float u0 = s01+s23, u1 = s45+s67, u2 = s89+sab, u3 = scd+e[14];
    const float sum = (u0+u1) + (u2+u3);
    const float nxt = emv + mx + __logf(sum);
    if (msk > 0 && j < 15) alpha = nxt;
  }
  float vz = (j < 15) ? (alpha + end_t[j]) : -3.0e38f;
  float mz = vz;
  #pragma unroll
  for (int off = 32; off > 0; off >>= 1) mz = fmaxf(mz, __shfl_xor(mz, off, 64));
  float se = (j < 15) ? __expf(vz - mz) : 0.f;
  #pragma unroll
  for (int off = 32; off > 0; off >>= 1) se += __shfl_xor(se, off, 64);
  const float logZ = mz + __logf(se);

  float sc = 0.f; int cnt = 0;
  for (int s = j; s < 512; s += 64) cnt += (mks[s] ? 1 : 0);
  for (int s = 1 + j; s < 512; s += 64) {
    if (mks[s]) {
      const int tp = tgs[s-1], tc = tgs[s];
      sc += trs[tp*15 + tc] + ems[s*15 + tc];
    }
  }
  #pragma unroll
  for (int off = 32; off > 0; off >>= 1) {
    sc  += __shfl_xor(sc, off, 64);
    cnt += __shfl_xor(cnt, off, 64);
  }
  if (j == 0) {
    const int t0 = tgs[0];
    sc += start_t[t0] + ems[t0];
    int last = cnt - 1; if (last < 0) last = 0;
    sc += end_t[tgs[last]];
    nllb[b] = logZ - sc;
  }
}

__global__ __launch_bounds__(64) void nll_reduce_kernel(const float* __restrict__ nllb,
                                                        float* __restrict__ out) {
  const int j = threadIdx.x;
  float v = (j < 32) ? nllb[j] : 0.f;
  #pragma unroll
  for (int off = 32; off > 0; off >>= 1) v += __shfl_xor(v, off, 64);
  if (j == 0) out[0] = v;
}

// ---------------- launch ----------------
extern "C" void kernel_launch(void* const* d_in, const int* in_sizes, int n_in,
                              void* d_out, int out_size, void* d_ws, size_t ws_size,
                              hipStream_t stream) {
  const float* x      = (const float*)d_in[0];
  const int*   tags   = (const int*)d_in[1];
  const int*   mask   = (const int*)d_in[2];
  const float* Wih_f  = (const float*)d_in[3];
  const float* Whh_f  = (const float*)d_in[4];
  const float* bih_f  = (const float*)d_in[5];
  const float* bhh_f  = (const float*)d_in[6];
  const float* Wih_b  = (const float*)d_in[7];
  const float* Whh_b  = (const float*)d_in[8];
  const float* bih_b  = (const float*)d_in[9];
  const float* bhh_b  = (const float*)d_in[10];
  const float* Wp     = (const float*)d_in[11];
  const float* bp     = (const float*)d_in[12];
  const float* trans  = (const float*)d_in[13];
  const float* start_t= (const float*)d_in[14];
  const float* end_t  = (const float*)d_in[15];
  float* out = (float*)d_out;

  char* ws = (char*)d_ws;
  size_t off = 0;
  auto alloc = [&](size_t bytes) { char* p = ws + off; off += (bytes + 255) & ~(size_t)255; return p; };
  __hip_bfloat16* xbf   = (__hip_bfloat16*)alloc((size_t)NM*NE*2);        // 25.2 MB
  __hip_bfloat16* Wihbf = (__hip_bfloat16*)alloc((size_t)1024*NE*2);      // 1.6 MB
  __hip_bfloat16* whhp  = (__hip_bfloat16*)alloc((size_t)2*512*128*2);    // 0.26 MB
  float*          biasp = (float*)alloc(1024*4);
  __hip_bfloat16* xqd   = (__hip_bfloat16*)alloc((size_t)2*NM*512*2);     // 33.6 MB
  float*          hf    = (float*)alloc((size_t)NM*128*4);                // 8.4 MB
  float*          hb    = (float*)alloc((size_t)NM*128*4);                // 8.4 MB
  float*          em    = (float*)alloc((size_t)NM*15*4);                 // 1.0 MB
  float*          nllb  = (float*)alloc(32*4);
  (void)ws_size; (void)in_sizes; (void)n_in; (void)out_size;

  cvt_bf16_kernel<<<2048, 256, 0, stream>>>(x, xbf, NM*NE/4);
  cvt_wih_perm<<<1024, 256, 0, stream>>>(Wih_f, Wih_b, Wihbf);
  cvt_whh_perm<<<1024, 128, 0, stream>>>(Whh_f, Whh_b, whhp);
  bias_perm_kernel<<<4, 256, 0, stream>>>(bih_f, bhh_f, bih_b, bhh_b, biasp);

  gemm_xproj<<<dim3(128, 8), 256, 0, stream>>>(xbf, Wihbf, biasp, xqd);
  lstm_mfma<<<16, 512, 0, stream>>>(xqd, whhp, hf, hb);
  em_kernel<<<64, 256, 0, stream>>>(hf, hb, Wp, bp, em);
  crf_kernel<<<32, 64, 0, stream>>>(em, tags, mask, trans, start_t, end_t, nllb);
  nll_reduce_kernel<<<1, 64, 0, stream>>>(nllb, out);
}

// Round 7
// 770.392 us; speedup vs baseline: 1.4911x; 1.4911x over previous
//
#include <hip/hip_runtime.h>
#include <hip/hip_bf16.h>
#include <cstdint>

typedef __attribute__((ext_vector_type(8))) short short8;
typedef __attribute__((ext_vector_type(4))) float f32x4;

#define NS 512
#define NB 32
#define NE 768
#define NH 128
#define NT 15
#define NM (NB*NS)      // 16384 rows, m = b*512 + s

__device__ __forceinline__ float bflo(unsigned int u){ return __builtin_bit_cast(float, u << 16); }
__device__ __forceinline__ float bfhi(unsigned int u){ return __builtin_bit_cast(float, u & 0xffff0000u); }
__device__ __forceinline__ float sigf(float x){ return __fdividef(1.f, 1.f + __expf(-x)); }
__device__ __forceinline__ float tanhf_(float x){ return 1.f - __fdividef(2.f, __expf(2.f*x) + 1.f); }

// raw workgroup barrier: LDS-drain only (no vmcnt!), compiler fences on both
// sides so LDS ops can't be moved across, but global loads/stores stay in flight.
__device__ __forceinline__ void lds_barrier() {
  asm volatile("s_waitcnt lgkmcnt(0)" ::: "memory");
  __builtin_amdgcn_s_barrier();
  asm volatile("" ::: "memory");
}

__device__ __forceinline__ void gload16(const void* g, void* l) {
#if __has_builtin(__builtin_amdgcn_global_load_lds)
  __builtin_amdgcn_global_load_lds((const __attribute__((address_space(1))) void*)g,
                                   (__attribute__((address_space(3))) void*)l, 16, 0, 0);
#else
  *(uint4*)l = *(const uint4*)g;
#endif
}

// ---------------- converts ----------------
__global__ void cvt_bf16_kernel(const float* __restrict__ in,
                                __hip_bfloat16* __restrict__ out, int n4) {
  int i = blockIdx.x*blockDim.x + threadIdx.x;
  int stride = gridDim.x*blockDim.x;
  for (int j = i; j < n4; j += stride) {
    float4 v = ((const float4*)in)[j];
    ushort4 o;
    o.x = __builtin_bit_cast(unsigned short, __float2bfloat16(v.x));
    o.y = __builtin_bit_cast(unsigned short, __float2bfloat16(v.y));
    o.z = __builtin_bit_cast(unsigned short, __float2bfloat16(v.z));
    o.w = __builtin_bit_cast(unsigned short, __float2bfloat16(v.w));
    ((ushort4*)out)[j] = o;
  }
}

// permuted row n = dir*512 + (j*4+g)  <- src row (g*128+j) of dir's weight
__global__ void cvt_wih_perm(const float* __restrict__ wf, const float* __restrict__ wb,
                             __hip_bfloat16* __restrict__ out) {
  const int n = blockIdx.x;           // 0..1023
  const int dir = n >> 9, cc = n & 511, j = cc >> 2, g = cc & 3;
  const float* src = (dir ? wb : wf) + (size_t)(g*128 + j)*768;
  __hip_bfloat16* dst = out + (size_t)n*768;
  for (int e = threadIdx.x; e < 768; e += 256) dst[e] = __float2bfloat16(src[e]);
}

__global__ void cvt_whh_perm(const float* __restrict__ wf, const float* __restrict__ wb,
                             __hip_bfloat16* __restrict__ out) {
  const int n = blockIdx.x;           // 0..1023 = dir*512+cc
  const int dir = n >> 9, cc = n & 511, j = cc >> 2, g = cc & 3;
  const float* src = (dir ? wb : wf) + (size_t)(g*128 + j)*128;
  __hip_bfloat16* dst = out + (size_t)n*128;
  if (threadIdx.x < 128) dst[threadIdx.x] = __float2bfloat16(src[threadIdx.x]);
}

__global__ void bias_perm_kernel(const float* __restrict__ bihf, const float* __restrict__ bhhf,
                                 const float* __restrict__ bihb, const float* __restrict__ bhhb,
                                 float* __restrict__ biasp) {
  const int n = blockIdx.x*blockDim.x + threadIdx.x;
  if (n >= 1024) return;
  const int dir = n >> 9, cc = n & 511, j = cc >> 2, g = cc & 3;
  const int src = g*128 + j;
  biasp[n] = dir ? (bihb[src] + bhhb[src]) : (bihf[src] + bhhf[src]);
}

// ---------------- xproj GEMM: A[16384x768] @ Bw[1024x768]^T -> xqd[2][NM][512] ----------------
__global__ __launch_bounds__(256, 2) void gemm_xproj(
    const __hip_bfloat16* __restrict__ A,
    const __hip_bfloat16* __restrict__ Bw,
    const float* __restrict__ biasp,
    __hip_bfloat16* __restrict__ xqd)        // [2][NM][512]
{
  __shared__ __align__(16) __hip_bfloat16 As[128*64];
  __shared__ __align__(16) __hip_bfloat16 Bs[128*64];
  const int bm = blockIdx.x * 128;
  const int bn = blockIdx.y * 128;
  const int tid = threadIdx.x;
  const int lane = tid & 63;
  const int wv = tid >> 6;
  const int wr = wv >> 1, wc = wv & 1;
  char* AsB = (char*)As;
  char* BsB = (char*)Bs;
  const char* Ab = (const char*)A;
  const char* Bb = (const char*)Bw;
  f32x4 acc[4][4] = {};

  for (int kt = 0; kt < 12; ++kt) {
    const int k0 = kt * 64;
    __syncthreads();
    #pragma unroll
    for (int i = 0; i < 4; ++i) {
      int fb = i*4096 + tid*16;
      int r  = fb >> 7;
      int cb = fb & 127;
      gload16(Ab + ((size_t)(bm + r)*768 + k0)*2 + cb, AsB + fb);
      gload16(Bb + ((size_t)(bn + r)*768 + k0)*2 + cb, BsB + fb);
    }
    __syncthreads();
    #pragma unroll
    for (int ks = 0; ks < 2; ++ks) {
      const int krow = ks*32 + ((lane >> 4) << 3);
      short8 af[4], bfr[4];
      #pragma unroll
      for (int m = 0; m < 4; ++m) {
        int row = wr*64 + m*16 + (lane & 15);
        af[m] = *(const short8*)(AsB + (row*64 + krow)*2);
      }
      #pragma unroll
      for (int n = 0; n < 4; ++n) {
        int row = wc*64 + n*16 + (lane & 15);
        bfr[n] = *(const short8*)(BsB + (row*64 + krow)*2);
      }
      #pragma unroll
      for (int m = 0; m < 4; ++m)
        #pragma unroll
        for (int n = 0; n < 4; ++n)
          acc[m][n] = __builtin_amdgcn_mfma_f32_16x16x32_bf16(af[m], bfr[n], acc[m][n], 0, 0, 0);
    }
  }
  #pragma unroll
  for (int m = 0; m < 4; ++m) {
    #pragma unroll
    for (int n = 0; n < 4; ++n) {
      const int col = bn + wc*64 + n*16 + (lane & 15);
      const float bv = biasp[col];
      const int dir = col >> 9;
      const int cc  = col & 511;
      #pragma unroll
      for (int jj = 0; jj < 4; ++jj) {
        const int row = bm + wr*64 + m*16 + ((lane >> 4)*4 + jj);
        xqd[((size_t)dir*NM + row)*512 + cc] = __float2bfloat16(acc[m][n][jj] + bv);
      }
    }
  }
}

// ---------------- LSTM recurrence via MFMA, two-phase, raw LDS-only barriers ----------------
// 16 blocks = (dir, bg), 4 batches each, 512 threads = 8 waves.
// Phase A: z[512x16] = Whhp[512x128] @ h[128x16] via MFMA; z -> swizzled z_lds.
// Phase B: thread (b4 = t&3, j = t>>2) computes one h; writes h into next
// B-fragment buffer (lane-linear layout, conflict-free) + global hout.
// Barriers drain lgkmcnt ONLY: hout stores and x prefetch stay in flight.
__global__ __launch_bounds__(512, 2) void lstm_mfma(
    const __hip_bfloat16* __restrict__ xqd,   // [2][NM][512] packed j*4+g, bias folded
    const __hip_bfloat16* __restrict__ whhp,  // [2][512][128] permuted rows
    float* __restrict__ hf,                   // [NM][128]
    float* __restrict__ hb)                   // [NM][128]
{
  __shared__ __align__(16) char hfrag[2*4224];   // [buf][kc:1056B][lane:16B] B-frag layout
  __shared__ __align__(16) float z_lds[4*520];   // [b][4*swz(j)] f32x4, swizzled

  const int bid = blockIdx.x;
  const int dir = bid >> 3, bg = bid & 7;
  const int t = threadIdx.x;
  const int w = t >> 6, l = t & 63;
  const int ln = l & 15, lp = l >> 4;

  // A-fragments: wave w rows (w*4+r)*16+ln, k = kc*32 + lp*8 + e. 64 dwords/lane.
  uint4 afu[4][4];
  {
    const char* wbase = (const char*)(whhp + (size_t)dir*512*128);
    #pragma unroll
    for (int r = 0; r < 4; ++r) {
      const int row = (w*4 + r)*16 + ln;
      #pragma unroll
      for (int kc = 0; kc < 4; ++kc)
        afu[r][kc] = *(const uint4*)(wbase + ((size_t)row*128 + lp*8 + kc*32)*2);
    }
  }
  // opaque pin once: asm-defined values stay materialized in registers.
  #pragma unroll
  for (int r = 0; r < 4; ++r)
    #pragma unroll
    for (int kc = 0; kc < 4; ++kc)
      asm volatile("" : "+v"(afu[r][kc].x), "+v"(afu[r][kc].y),
                        "+v"(afu[r][kc].z), "+v"(afu[r][kc].w));

  for (int i = t; i < 2*4224/4; i += 512) ((int*)hfrag)[i] = 0;

  // phase-B identity: b4 = t&3 (varies within wave -> spread h-write banks,
  // coalesced x/hout), j = t>>2.
  const int b4 = t & 3, j = t >> 2;
  const int bsafe = bg*4 + b4;
  const int jsw = j ^ ((j >> 3) & 7);
  const int woff = (j >> 5)*1056 + ((j >> 3) & 3)*256 + b4*16 + (j & 7)*2;
  const __hip_bfloat16* xb = xqd + ((size_t)dir*NM + (size_t)bsafe*512)*512 + j*4;
  float* hout = (dir ? hb : hf) + (size_t)bsafe*512*128 + j;

  float c = 0.f;
  uint2 xc, xn;
  {
    const int s0 = dir ? 511 : 0, s1 = dir ? 510 : 1;
    xc = *(const uint2*)(xb + (size_t)s0*512);
    xn = *(const uint2*)(xb + (size_t)s1*512);
  }
  __syncthreads();   // prologue only

  int buf = 0;
  for (int si = 0; si < 512; ++si) {
    const int s = dir ? (511 - si) : si;

    // ---- phase A: B-fragments (lane-linear, conflict-free) + 16 MFMA ----
    short8 bfv[4];
    #pragma unroll
    for (int kc = 0; kc < 4; ++kc)
      bfv[kc] = *(const short8*)(hfrag + buf*4224 + kc*1056 + l*16);

    f32x4 acc[4];
    #pragma unroll
    for (int r = 0; r < 4; ++r) {
      acc[r] = f32x4{0.f, 0.f, 0.f, 0.f};
      #pragma unroll
      for (int kc = 0; kc < 4; ++kc)
        acc[r] = __builtin_amdgcn_mfma_f32_16x16x32_bf16(
                   __builtin_bit_cast(short8, afu[r][kc]), bfv[kc], acc[r], 0, 0, 0);
    }

    // x prefetch for si+2 (stays in flight across the LDS-only barriers)
    uint2 x2 = xn;
    if (si + 2 < 512) {
      const int sn = dir ? (509 - si) : (si + 2);
      x2 = *(const uint2*)(xb + (size_t)sn*512);
    }

    // publish z (real batch cols ln<4 only), XOR-swizzled -> conflict-free
    if (ln < 4) {
      #pragma unroll
      for (int r = 0; r < 4; ++r) {
        const int jw = (w*4 + r)*4 + lp;
        const int js = jw ^ ((jw >> 3) & 7);
        *(f32x4*)&z_lds[ln*520 + 4*js] = acc[r];
      }
    }
    lds_barrier();

    // ---- phase B: one h per thread ----
    const f32x4 zv = *(const f32x4*)&z_lds[b4*520 + 4*jsw];
    const float zi = zv[0] + bflo(xc.x);
    const float zf = zv[1] + bfhi(xc.x);
    const float zg = zv[2] + bflo(xc.y);
    const float zo = zv[3] + bfhi(xc.y);
    c = sigf(zf)*c + sigf(zi)*tanhf_(zg);
    const float h = sigf(zo)*tanhf_(c);

    *(short*)(hfrag + (buf ^ 1)*4224 + woff) =
        (short)__builtin_bit_cast(unsigned short, __float2bfloat16(h));
    hout[(size_t)s*128] = h;          // fire-and-forget (never drained in-loop)

    xc = xn; xn = x2;
    lds_barrier();
    buf ^= 1;
  }
}

// ---------------- emissions: em[m][t] = [hf|hb][m] . Wp[t] + bp[t] ----------------
__global__ __launch_bounds__(256) void em_kernel(
    const float* __restrict__ hf, const float* __restrict__ hb,
    const float* __restrict__ Wp, const float* __restrict__ bp,
    float* __restrict__ em)
{
  __shared__ float wps[15*256];
  __shared__ float bps[15];
  const int tid = threadIdx.x;
  for (int i = tid; i < 15*256; i += 256) wps[i] = Wp[i];
  if (tid < 15) bps[tid] = bp[tid];
  __syncthreads();
  const size_t m = (size_t)blockIdx.x*256 + tid;
  float acc[15];
  #pragma unroll
  for (int t2 = 0; t2 < 15; ++t2) acc[t2] = bps[t2];
  const float4* hf4 = (const float4*)(hf + m*128);
  const float4* hb4 = (const float4*)(hb + m*128);
  for (int kc = 0; kc < 32; ++kc) {
    float4 hv = hf4[kc];
    #pragma unroll
    for (int t2 = 0; t2 < 15; ++t2)
      acc[t2] += hv.x*wps[t2*256 + kc*4+0] + hv.y*wps[t2*256 + kc*4+1]
               + hv.z*wps[t2*256 + kc*4+2] + hv.w*wps[t2*256 + kc*4+3];
  }
  for (int kc = 0; kc < 32; ++kc) {
    float4 hv = hb4[kc];
    #pragma unroll
    for (int t2 = 0; t2 < 15; ++t2)
      acc[t2] += hv.x*wps[t2*256 + 128 + kc*4+0] + hv.y*wps[t2*256 + 128 + kc*4+1]
               + hv.z*wps[t2*256 + 128 + kc*4+2] + hv.w*wps[t2*256 + 128 + kc*4+3];
  }
  float* eo = em + m*15;
  #pragma unroll
  for (int t2 = 0; t2 < 15; ++t2) eo[t2] = acc[t2];
}

// ---------------- CRF NLL: one block (1 wave) per batch -> partial per b ----------------
__global__ __launch_bounds__(64) void crf_kernel(
    const float* __restrict__ em,
    const int* __restrict__ tags, const int* __restrict__ mask,
    const float* __restrict__ trans, const float* __restrict__ start_t,
    const float* __restrict__ end_t, float* __restrict__ nllb)
{
  __shared__ __align__(16) float ems[512*15];
  __shared__ float trs[225];
  __shared__ int tgs[512];
  __shared__ int mks[512];
  const int b = blockIdx.x, j = threadIdx.x;
  const float* emb = em + (size_t)b*512*15;
  {
    const float4* s4 = (const float4*)emb;
    float4* d4 = (float4*)ems;
    for (int i = j; i < 512*15/4; i += 64) d4[i] = s4[i];
    for (int i = j; i < 512; i += 64) { tgs[i] = tags[b*512+i]; mks[i] = mask[b*512+i]; }
    for (int i = j; i < 225; i += 64) trs[i] = trans[i];
  }
  __syncthreads();

  float trc[15];
  #pragma unroll
  for (int i = 0; i < 15; ++i) trc[i] = (j < 15) ? trs[i*15 + j] : 0.f;

  float alpha = (j < 15) ? (start_t[j] + ems[j]) : -3.0e38f;
  for (int s = 1; s < 512; ++s) {
    const float emv = (j < 15) ? ems[s*15 + j] : 0.f;
    const int msk = mks[s];
    float v[15];
    #pragma unroll
    for (int i = 0; i < 15; ++i) {
      const float ai = __shfl(alpha, i, 64);
      v[i] = ai + trc[i];
    }
    const float t01 = fmaxf(v[0], v[1]),  t23 = fmaxf(v[2], v[3]);
    const float t45 = fmaxf(v[4], v[5]),  t67 = fmaxf(v[6], v[7]);
    const float t89 = fmaxf(v[8], v[9]),  tab = fmaxf(v[10], v[11]);
    const float tcd = fmaxf(v[12], v[13]);
    const float q0 = fmaxf(t01, t23), q1 = fmaxf(t45, t67);
    const float q2 = fmaxf(t89, tab), q3 = fmaxf(tcd, v[14]);
    const float mx = fmaxf(fmaxf(q0, q1), fmaxf(q2, q3));
    float e[15];
    #pragma unroll
    for (int i = 0; i < 15; ++i) e[i] = __expf(v[i] - mx);
    const float s01 = e[0]+e[1], s23 = e[2]+e[3], s45 = e[4]+e[5], s67 = e[6]+e[7];
    const float s89 = e[8]+e[9], sab = e[10]+e[11], scd = e[12]+e[13];
    const float u0 = s01+s23, u1 = s45+s67, u2 = s89+sab, u3 = scd+e[14];
    const float sum = (u0+u1) + (u2+u3);
    const float nxt = emv + mx + __logf(sum);
    if (msk > 0 && j < 15) alpha = nxt;
  }
  float vz = (j < 15) ? (alpha + end_t[j]) : -3.0e38f;
  float mz = vz;
  #pragma unroll
  for (int off = 32; off > 0; off >>= 1) mz = fmaxf(mz, __shfl_xor(mz, off, 64));
  float se = (j < 15) ? __expf(vz - mz) : 0.f;
  #pragma unroll
  for (int off = 32; off > 0; off >>= 1) se += __shfl_xor(se, off, 64);
  const float logZ = mz + __logf(se);

  float sc = 0.f; int cnt = 0;
  for (int s = j; s < 512; s += 64) cnt += (mks[s] ? 1 : 0);
  for (int s = 1 + j; s < 512; s += 64) {
    if (mks[s]) {
      const int tp = tgs[s-1], tc = tgs[s];
      sc += trs[tp*15 + tc] + ems[s*15 + tc];
    }
  }
  #pragma unroll
  for (int off = 32; off > 0; off >>= 1) {
    sc  += __shfl_xor(sc, off, 64);
    cnt += __shfl_xor(cnt, off, 64);
  }
  if (j == 0) {
    const int t0 = tgs[0];
    sc += start_t[t0] + ems[t0];
    int last = cnt - 1; if (last < 0) last = 0;
    sc += end_t[tgs[last]];
    nllb[b] = logZ - sc;
  }
}

__global__ __launch_bounds__(64) void nll_reduce_kernel(const float* __restrict__ nllb,
                                                        float* __restrict__ out) {
  const int j = threadIdx.x;
  float v = (j < 32) ? nllb[j] : 0.f;
  #pragma unroll
  for (int off = 32; off > 0; off >>= 1) v += __shfl_xor(v, off, 64);
  if (j == 0) out[0] = v;
}

// ---------------- launch ----------------
extern "C" void kernel_launch(void* const* d_in, const int* in_sizes, int n_in,
                              void* d_out, int out_size, void* d_ws, size_t ws_size,
                              hipStream_t stream) {
  const float* x      = (const float*)d_in[0];
  const int*   tags   = (const int*)d_in[1];
  const int*   mask   = (const int*)d_in[2];
  const float* Wih_f  = (const float*)d_in[3];
  const float* Whh_f  = (const float*)d_in[4];
  const float* bih_f  = (const float*)d_in[5];
  const float* bhh_f  = (const float*)d_in[6];
  const float* Wih_b  = (const float*)d_in[7];
  const float* Whh_b  = (const float*)d_in[8];
  const float* bih_b  = (const float*)d_in[9];
  const float* bhh_b  = (const float*)d_in[10];
  const float* Wp     = (const float*)d_in[11];
  const float* bp     = (const float*)d_in[12];
  const float* trans  = (const float*)d_in[13];
  const float* start_t= (const float*)d_in[14];
  const float* end_t  = (const float*)d_in[15];
  float* out = (float*)d_out;

  char* ws = (char*)d_ws;
  size_t off = 0;
  auto alloc = [&](size_t bytes) { char* p = ws + off; off += (bytes + 255) & ~(size_t)255; return p; };
  __hip_bfloat16* xbf   = (__hip_bfloat16*)alloc((size_t)NM*NE*2);        // 25.2 MB
  __hip_bfloat16* Wihbf = (__hip_bfloat16*)alloc((size_t)1024*NE*2);      // 1.6 MB
  __hip_bfloat16* whhp  = (__hip_bfloat16*)alloc((size_t)2*512*128*2);    // 0.26 MB
  float*          biasp = (float*)alloc(1024*4);
  __hip_bfloat16* xqd   = (__hip_bfloat16*)alloc((size_t)2*NM*512*2);     // 33.6 MB
  float*          hf    = (float*)alloc((size_t)NM*128*4);                // 8.4 MB
  float*          hb    = (float*)alloc((size_t)NM*128*4);                // 8.4 MB
  float*          em    = (float*)alloc((size_t)NM*15*4);                 // 1.0 MB
  float*          nllb  = (float*)alloc(32*4);
  (void)ws_size; (void)in_sizes; (void)n_in; (void)out_size;

  cvt_bf16_kernel<<<2048, 256, 0, stream>>>(x, xbf, NM*NE/4);
  cvt_wih_perm<<<1024, 256, 0, stream>>>(Wih_f, Wih_b, Wihbf);
  cvt_whh_perm<<<1024, 128, 0, stream>>>(Whh_f, Whh_b, whhp);
  bias_perm_kernel<<<4, 256, 0, stream>>>(bih_f, bhh_f, bih_b, bhh_b, biasp);

  gemm_xproj<<<dim3(128, 8), 256, 0, stream>>>(xbf, Wihbf, biasp, xqd);
  lstm_mfma<<<16, 512, 0, stream>>>(xqd, whhp, hf, hb);
  em_kernel<<<64, 256, 0, stream>>>(hf, hb, Wp, bp, em);
  crf_kernel<<<32, 64, 0, stream>>>(em, tags, mask, trans, start_t, end_t, nllb);
  nll_reduce_kernel<<<1, 64, 0, stream>>>(nllb, out);
}

// Round 9
// 681.608 us; speedup vs baseline: 1.6853x; 1.1303x over previous
//
#include <hip/hip_runtime.h>
#include <hip/hip_bf16.h>
#include <cstdint>

typedef __attribute__((ext_vector_type(8))) short short8;
typedef __attribute__((ext_vector_type(4))) float f32x4;

#define NS 512
#define NB 32
#define NE 768
#define NH 128
#define NT 15
#define NM (NB*NS)      // 16384 rows, m = b*512 + s

__device__ __forceinline__ float bflo(unsigned int u){ return __builtin_bit_cast(float, u << 16); }
__device__ __forceinline__ float bfhi(unsigned int u){ return __builtin_bit_cast(float, u & 0xffff0000u); }
__device__ __forceinline__ float sigf(float x){ return __fdividef(1.f, 1.f + __expf(-x)); }
__device__ __forceinline__ float tanhf_(float x){ return 1.f - __fdividef(2.f, __expf(2.f*x) + 1.f); }

// raw workgroup barrier: LDS-drain only (no vmcnt), fences so LDS ops can't
// cross, but global loads/stores stay in flight.
__device__ __forceinline__ void lds_barrier() {
  asm volatile("s_waitcnt lgkmcnt(0)" ::: "memory");
  __builtin_amdgcn_s_barrier();
  asm volatile("" ::: "memory");
}

__device__ __forceinline__ void gload16(const void* g, void* l) {
#if __has_builtin(__builtin_amdgcn_global_load_lds)
  __builtin_amdgcn_global_load_lds((const __attribute__((address_space(1))) void*)g,
                                   (__attribute__((address_space(3))) void*)l, 16, 0, 0);
#else
  *(uint4*)l = *(const uint4*)g;
#endif
}

// ---------------- converts ----------------
__global__ void cvt_bf16_kernel(const float* __restrict__ in,
                                __hip_bfloat16* __restrict__ out, int n4) {
  int i = blockIdx.x*blockDim.x + threadIdx.x;
  int stride = gridDim.x*blockDim.x;
  for (int j = i; j < n4; j += stride) {
    float4 v = ((const float4*)in)[j];
    ushort4 o;
    o.x = __builtin_bit_cast(unsigned short, __float2bfloat16(v.x));
    o.y = __builtin_bit_cast(unsigned short, __float2bfloat16(v.y));
    o.z = __builtin_bit_cast(unsigned short, __float2bfloat16(v.z));
    o.w = __builtin_bit_cast(unsigned short, __float2bfloat16(v.w));
    ((ushort4*)out)[j] = o;
  }
}

// permuted row n = dir*512 + (j*4+g)  <- src row (g*128+j) of dir's weight
__global__ void cvt_wih_perm(const float* __restrict__ wf, const float* __restrict__ wb,
                             __hip_bfloat16* __restrict__ out) {
  const int n = blockIdx.x;           // 0..1023
  const int dir = n >> 9, cc = n & 511, j = cc >> 2, g = cc & 3;
  const float* src = (dir ? wb : wf) + (size_t)(g*128 + j)*768;
  __hip_bfloat16* dst = out + (size_t)n*768;
  for (int e = threadIdx.x; e < 768; e += 256) dst[e] = __float2bfloat16(src[e]);
}

__global__ void cvt_whh_perm(const float* __restrict__ wf, const float* __restrict__ wb,
                             __hip_bfloat16* __restrict__ out) {
  const int n = blockIdx.x;           // 0..1023 = dir*512+cc
  const int dir = n >> 9, cc = n & 511, j = cc >> 2, g = cc & 3;
  const float* src = (dir ? wb : wf) + (size_t)(g*128 + j)*128;
  __hip_bfloat16* dst = out + (size_t)n*128;
  if (threadIdx.x < 128) dst[threadIdx.x] = __float2bfloat16(src[threadIdx.x]);
}

__global__ void bias_perm_kernel(const float* __restrict__ bihf, const float* __restrict__ bhhf,
                                 const float* __restrict__ bihb, const float* __restrict__ bhhb,
                                 float* __restrict__ biasp) {
  const int n = blockIdx.x*blockDim.x + threadIdx.x;
  if (n >= 1024) return;
  const int dir = n >> 9, cc = n & 511, j = cc >> 2, g = cc & 3;
  const int src = g*128 + j;
  biasp[n] = dir ? (bihb[src] + bhhb[src]) : (bihf[src] + bhhf[src]);
}

// ---------------- xproj GEMM: A[16384x768] @ Bw[1024x768]^T -> xqd[2][NM][512] ----------------
__global__ __launch_bounds__(256, 2) void gemm_xproj(
    const __hip_bfloat16* __restrict__ A,
    const __hip_bfloat16* __restrict__ Bw,
    const float* __restrict__ biasp,
    __hip_bfloat16* __restrict__ xqd)        // [2][NM][512]
{
  __shared__ __align__(16) __hip_bfloat16 As[128*64];
  __shared__ __align__(16) __hip_bfloat16 Bs[128*64];
  const int bm = blockIdx.x * 128;
  const int bn = blockIdx.y * 128;
  const int tid = threadIdx.x;
  const int lane = tid & 63;
  const int wv = tid >> 6;
  const int wr = wv >> 1, wc = wv & 1;
  char* AsB = (char*)As;
  char* BsB = (char*)Bs;
  const char* Ab = (const char*)A;
  const char* Bb = (const char*)Bw;
  f32x4 acc[4][4] = {};

  for (int kt = 0; kt < 12; ++kt) {
    const int k0 = kt * 64;
    __syncthreads();
    #pragma unroll
    for (int i = 0; i < 4; ++i) {
      int fb = i*4096 + tid*16;
      int r  = fb >> 7;
      int cb = fb & 127;
      gload16(Ab + ((size_t)(bm + r)*768 + k0)*2 + cb, AsB + fb);
      gload16(Bb + ((size_t)(bn + r)*768 + k0)*2 + cb, BsB + fb);
    }
    __syncthreads();
    #pragma unroll
    for (int ks = 0; ks < 2; ++ks) {
      const int krow = ks*32 + ((lane >> 4) << 3);
      short8 af[4], bfr[4];
      #pragma unroll
      for (int m = 0; m < 4; ++m) {
        int row = wr*64 + m*16 + (lane & 15);
        af[m] = *(const short8*)(AsB + (row*64 + krow)*2);
      }
      #pragma unroll
      for (int n = 0; n < 4; ++n) {
        int row = wc*64 + n*16 + (lane & 15);
        bfr[n] = *(const short8*)(BsB + (row*64 + krow)*2);
      }
      #pragma unroll
      for (int m = 0; m < 4; ++m)
        #pragma unroll
        for (int n = 0; n < 4; ++n)
          acc[m][n] = __builtin_amdgcn_mfma_f32_16x16x32_bf16(af[m], bfr[n], acc[m][n], 0, 0, 0);
    }
  }
  #pragma unroll
  for (int m = 0; m < 4; ++m) {
    #pragma unroll
    for (int n = 0; n < 4; ++n) {
      const int col = bn + wc*64 + n*16 + (lane & 15);
      const float bv = biasp[col];
      const int dir = col >> 9;
      const int cc  = col & 511;
      #pragma unroll
      for (int jj = 0; jj < 4; ++jj) {
        const int row = bm + wr*64 + m*16 + ((lane >> 4)*4 + jj);
        xqd[((size_t)dir*NM + row)*512 + cc] = __float2bfloat16(acc[m][n][jj] + bv);
      }
    }
  }
}

// ---------------- LSTM recurrence via MFMA: AGPR weights + 16-step reg-batched x ----------------
// 16 blocks = (dir, bg), 4 batches each, 512 threads = 8 waves.
// Phase A: z[512x16] = Whhp @ h via MFMA (A-frags pinned in AGPRs).
// Phase B: thread (b4=t&3, j=t>>2) computes one h; h -> next B-frag buffer + global.
// x pre-activations consumed from a fully-unrolled 16-step register ping-pong
// (xsA/xsB); one load per step issued 16 steps ahead -> no per-step L3 wait.
__global__ __launch_bounds__(512) __attribute__((amdgpu_waves_per_eu(1, 2)))
void lstm_mfma(
    const __hip_bfloat16* __restrict__ xqd,   // [2][NM][512] packed j*4+g, bias folded
    const __hip_bfloat16* __restrict__ whhp,  // [2][512][128] permuted rows
    float* __restrict__ hf,                   // [NM][128]
    float* __restrict__ hb)                   // [NM][128]
{
  __shared__ __align__(16) char hfrag[2*4224];   // [buf][kc:1056B][lane:16B] B-frag layout
  __shared__ __align__(16) float z_lds[4*520];   // [b][4*swz(j)] f32x4, swizzled

  const int bid = blockIdx.x;
  const int dir = bid >> 3, bg = bid & 7;
  const int t = threadIdx.x;
  const int w = t >> 6, l = t & 63;
  const int ln = l & 15, lp = l >> 4;

  // A-fragments: wave w rows (w*4+r)*16+ln, k = kc*32 + lp*8 + e. 64 dwords/lane.
  uint4 afu[4][4];
  {
    const char* wbase = (const char*)(whhp + (size_t)dir*512*128);
    #pragma unroll
    for (int r = 0; r < 4; ++r) {
      const int row = (w*4 + r)*16 + ln;
      #pragma unroll
      for (int kc = 0; kc < 4; ++kc)
        afu[r][kc] = *(const uint4*)(wbase + ((size_t)row*128 + lp*8 + kc*32)*2);
    }
  }

  for (int i = t; i < 2*4224/4; i += 512) ((int*)hfrag)[i] = 0;

  // phase-B identity
  const int b4 = t & 3, j = t >> 2;
  const int bsafe = bg*4 + b4;
  const int jsw = j ^ ((j >> 3) & 7);
  const int woff = (j >> 5)*1056 + ((j >> 3) & 3)*256 + b4*16 + (j & 7)*2;
  const __hip_bfloat16* xb = xqd + ((size_t)dir*NM + (size_t)bsafe*512)*512 + j*4;
  float* hout = (dir ? hb : hf) + (size_t)bsafe*512*128 + j;

  float c = 0.f;

  // 16-step x register ping-pong, fully static indexing
  uint2 xsA[16], xsB[16];
  #pragma unroll
  for (int k = 0; k < 16; ++k) {
    const int si = k;
    const int sl = dir ? (511 - si) : si;
    xsA[k] = *(const uint2*)(xb + (size_t)sl*512);
  }
  __syncthreads();   // prologue only (drains the 16 loads once)

  for (int p = 0; p < 16; ++p) {            // 16 pairs x 32 steps = 512
    // pin weights to AGPRs each pair: AGPRs carry no VALU pressure, MFMA reads
    // them natively -> allocator has no incentive to spill/remat.
    #pragma unroll
    for (int r = 0; r < 4; ++r)
      #pragma unroll
      for (int kc = 0; kc < 4; ++kc)
        asm volatile("" : "+a"(afu[r][kc].x), "+a"(afu[r][kc].y),
                          "+a"(afu[r][kc].z), "+a"(afu[r][kc].w));

    #pragma unroll
    for (int kk = 0; kk < 32; ++kk) {
      const int si = p*32 + kk;
      const int s = dir ? (511 - si) : si;
      const int bufc = kk & 1;

      // ---- phase A: B-fragments (lane-linear, conflict-free) + 16 MFMA ----
      short8 bfv[4];
      #pragma unroll
      for (int kc = 0; kc < 4; ++kc)
        bfv[kc] = *(const short8*)(hfrag + bufc*4224 + kc*1056 + l*16);

      f32x4 acc[4];
      #pragma unroll
      for (int r = 0; r < 4; ++r) {
        acc[r] = f32x4{0.f, 0.f, 0.f, 0.f};
        #pragma unroll
        for (int kc = 0; kc < 4; ++kc)
          acc[r] = __builtin_amdgcn_mfma_f32_16x16x32_bf16(
                     __builtin_bit_cast(short8, afu[r][kc]), bfv[kc], acc[r], 0, 0, 0);
      }

      // ---- issue ONE x prefetch: step (si+16), into the other array slot ----
      {
        const int fi = si + 16;
        if (fi < 512) {
          const int fl = dir ? (511 - fi) : fi;
          if (kk < 16) xsB[kk]      = *(const uint2*)(xb + (size_t)fl*512);
          else         xsA[kk - 16] = *(const uint2*)(xb + (size_t)fl*512);
        }
      }

      // publish z (real batch cols ln<4 only), XOR-swizzled
      if (ln < 4) {
        #pragma unroll
        for (int r = 0; r < 4; ++r) {
          const int jw = (w*4 + r)*4 + lp;
          const int js = jw ^ ((jw >> 3) & 7);
          *(f32x4*)&z_lds[ln*520 + 4*js] = acc[r];
        }
      }
      lds_barrier();

      // ---- phase B: one h per thread ----
      const uint2 xu = (kk < 16) ? xsA[kk] : xsB[kk - 16];
      const f32x4 zv = *(const f32x4*)&z_lds[b4*520 + 4*jsw];
      const float zi = zv[0] + bflo(xu.x);
      const float zf = zv[1] + bfhi(xu.x);
      const float zg = zv[2] + bflo(xu.y);
      const float zo = zv[3] + bfhi(xu.y);
      c = sigf(zf)*c + sigf(zi)*tanhf_(zg);
      const float h = sigf(zo)*tanhf_(c);

      *(short*)(hfrag + (bufc ^ 1)*4224 + woff) =
          (short)__builtin_bit_cast(unsigned short, __float2bfloat16(h));
      hout[(size_t)s*128] = h;          // fire-and-forget

      lds_barrier();
    }
  }
}

// ---------------- emissions: em[m][t] = [hf|hb][m] . Wp[t] + bp[t] ----------------
__global__ __launch_bounds__(256) void em_kernel(
    const float* __restrict__ hf, const float* __restrict__ hb,
    const float* __restrict__ Wp, const float* __restrict__ bp,
    float* __restrict__ em)
{
  __shared__ float wps[15*256];
  __shared__ float bps[15];
  const int tid = threadIdx.x;
  for (int i = tid; i < 15*256; i += 256) wps[i] = Wp[i];
  if (tid < 15) bps[tid] = bp[tid];
  __syncthreads();
  const size_t m = (size_t)blockIdx.x*256 + tid;
  float acc[15];
  #pragma unroll
  for (int t2 = 0; t2 < 15; ++t2) acc[t2] = bps[t2];
  const float4* hf4 = (const float4*)(hf + m*128);
  const float4* hb4 = (const float4*)(hb + m*128);
  for (int kc = 0; kc < 32; ++kc) {
    float4 hv = hf4[kc];
    #pragma unroll
    for (int t2 = 0; t2 < 15; ++t2)
      acc[t2] += hv.x*wps[t2*256 + kc*4+0] + hv.y*wps[t2*256 + kc*4+1]
               + hv.z*wps[t2*256 + kc*4+2] + hv.w*wps[t2*256 + kc*4+3];
  }
  for (int kc = 0; kc < 32; ++kc) {
    float4 hv = hb4[kc];
    #pragma unroll
    for (int t2 = 0; t2 < 15; ++t2)
      acc[t2] += hv.x*wps[t2*256 + 128 + kc*4+0] + hv.y*wps[t2*256 + 128 + kc*4+1]
               + hv.z*wps[t2*256 + 128 + kc*4+2] + hv.w*wps[t2*256 + 128 + kc*4+3];
  }
  float* eo = em + m*15;
  #pragma unroll
  for (int t2 = 0; t2 < 15; ++t2) eo[t2] = acc[t2];
}

// ---------------- CRF NLL: one block (1 wave) per batch -> partial per b ----------------
__global__ __launch_bounds__(64) void crf_kernel(
    const float* __restrict__ em,
    const int* __restrict__ tags, const int* __restrict__ mask,
    const float* __restrict__ trans, const float* __restrict__ start_t,
    const float* __restrict__ end_t, float* __restrict__ nllb)
{
  __shared__ __align__(16) float ems[512*15];
  __shared__ float trs[225];
  __shared__ int tgs[512];
  __shared__ int mks[512];
  const int b = blockIdx.x, j = threadIdx.x;
  const float* emb = em + (size_t)b*512*15;
  {
    const float4* s4 = (const float4*)emb;
    float4* d4 = (float4*)ems;
    for (int i = j; i < 512*15/4; i += 64) d4[i] = s4[i];
    for (int i = j; i < 512; i += 64) { tgs[i] = tags[b*512+i]; mks[i] = mask[b*512+i]; }
    for (int i = j; i < 225; i += 64) trs[i] = trans[i];
  }
  __syncthreads();

  float trc[15];
  #pragma unroll
  for (int i = 0; i < 15; ++i) trc[i] = (j < 15) ? trs[i*15 + j] : 0.f;

  float alpha = (j < 15) ? (start_t[j] + ems[j]) : -3.0e38f;
  for (int s = 1; s < 512; ++s) {
    const float emv = (j < 15) ? ems[s*15 + j] : 0.f;
    const int msk = mks[s];
    float v[15];
    #pragma unroll
    for (int i = 0; i < 15; ++i) {
      const float ai = __shfl(alpha, i, 64);
      v[i] = ai + trc[i];
    }
    const float t01 = fmaxf(v[0], v[1]),  t23 = fmaxf(v[2], v[3]);
    const float t45 = fmaxf(v[4], v[5]),  t67 = fmaxf(v[6], v[7]);
    const float t89 = fmaxf(v[8], v[9]),  tab = fmaxf(v[10], v[11]);
    const float tcd = fmaxf(v[12], v[13]);
    const float q0 = fmaxf(t01, t23), q1 = fmaxf(t45, t67);
    const float q2 = fmaxf(t89, tab), q3 = fmaxf(tcd, v[14]);
    const float mx = fmaxf(fmaxf(q0, q1), fmaxf(q2, q3));
    float e[15];
    #pragma unroll
    for (int i = 0; i < 15; ++i) e[i] = __expf(v[i] - mx);
    const float s01 = e[0]+e[1], s23 = e[2]+e[3], s45 = e[4]+e[5], s67 = e[6]+e[7];
    const float s89 = e[8]+e[9], sab = e[10]+e[11], scd = e[12]+e[13];
    const float u0 = s01+s23, u1 = s45+s67, u2 = s89+sab, u3 = scd+e[14];
    const float sum = (u0+u1) + (u2+u3);
    const float nxt = emv + mx + __logf(sum);
    if (msk > 0 && j < 15) alpha = nxt;
  }
  float vz = (j < 15) ? (alpha + end_t[j]) : -3.0e38f;
  float mz = vz;
  #pragma unroll
  for (int off = 32; off > 0; off >>= 1) mz = fmaxf(mz, __shfl_xor(mz, off, 64));
  float se = (j < 15) ? __expf(vz - mz) : 0.f;
  #pragma unroll
  for (int off = 32; off > 0; off >>= 1) se += __shfl_xor(se, off, 64);
  const float logZ = mz + __logf(se);

  float sc = 0.f; int cnt = 0;
  for (int s = j; s < 512; s += 64) cnt += (mks[s] ? 1 : 0);
  for (int s = 1 + j; s < 512; s += 64) {
    if (mks[s]) {
      const int tp = tgs[s-1], tc = tgs[s];
      sc += trs[tp*15 + tc] + ems[s*15 + tc];
    }
  }
  #pragma unroll
  for (int off = 32; off > 0; off >>= 1) {
    sc  += __shfl_xor(sc, off, 64);
    cnt += __shfl_xor(cnt, off, 64);
  }
  if (j == 0) {
    const int t0 = tgs[0];
    sc += start_t[t0] + ems[t0];
    int last = cnt - 1; if (last < 0) last = 0;
    sc += end_t[tgs[last]];
    nllb[b] = logZ - sc;
  }
}

__global__ __launch_bounds__(64) void nll_reduce_kernel(const float* __restrict__ nllb,
                                                        float* __restrict__ out) {
  const int j = threadIdx.x;
  float v = (j < 32) ? nllb[j] : 0.f;
  #pragma unroll
  for (int off = 32; off > 0; off >>= 1) v += __shfl_xor(v, off, 64);
  if (j == 0) out[0] = v;
}

// ---------------- launch ----------------
extern "C" void kernel_launch(void* const* d_in, const int* in_sizes, int n_in,
                              void* d_out, int out_size, void* d_ws, size_t ws_size,
                              hipStream_t stream) {
  const float* x      = (const float*)d_in[0];
  const int*   tags   = (const int*)d_in[1];
  const int*   mask   = (const int*)d_in[2];
  const float* Wih_f  = (const float*)d_in[3];
  const float* Whh_f  = (const float*)d_in[4];
  const float* bih_f  = (const float*)d_in[5];
  const float* bhh_f  = (const float*)d_in[6];
  const float* Wih_b  = (const float*)d_in[7];
  const float* Whh_b  = (const float*)d_in[8];
  const float* bih_b  = (const float*)d_in[9];
  const float* bhh_b  = (const float*)d_in[10];
  const float* Wp     = (const float*)d_in[11];
  const float* bp     = (const float*)d_in[12];
  const float* trans  = (const float*)d_in[13];
  const float* start_t= (const float*)d_in[14];
  const float* end_t  = (const float*)d_in[15];
  float* out = (float*)d_out;

  char* ws = (char*)d_ws;
  size_t off = 0;
  auto alloc = [&](size_t bytes) { char* p = ws + off; off += (bytes + 255) & ~(size_t)255; return p; };
  __hip_bfloat16* xbf   = (__hip_bfloat16*)alloc((size_t)NM*NE*2);        // 25.2 MB
  __hip_bfloat16* Wihbf = (__hip_bfloat16*)alloc((size_t)1024*NE*2);      // 1.6 MB
  __hip_bfloat16* whhp  = (__hip_bfloat16*)alloc((size_t)2*512*128*2);    // 0.26 MB
  float*          biasp = (float*)alloc(1024*4);
  __hip_bfloat16* xqd   = (__hip_bfloat16*)alloc((size_t)2*NM*512*2);     // 33.6 MB
  float*          hf    = (float*)alloc((size_t)NM*128*4);                // 8.4 MB
  float*          hb    = (float*)alloc((size_t)NM*128*4);                // 8.4 MB
  float*          em    = (float*)alloc((size_t)NM*15*4);                 // 1.0 MB
  float*          nllb  = (float*)alloc(32*4);
  (void)ws_size; (void)in_sizes; (void)n_in; (void)out_size;

  cvt_bf16_kernel<<<2048, 256, 0, stream>>>(x, xbf, NM*NE/4);
  cvt_wih_perm<<<1024, 256, 0, stream>>>(Wih_f, Wih_b, Wihbf);
  cvt_whh_perm<<<1024, 128, 0, stream>>>(Whh_f, Whh_b, whhp);
  bias_perm_kernel<<<4, 256, 0, stream>>>(bih_f, bhh_f, bih_b, bhh_b, biasp);

  gemm_xproj<<<dim3(128, 8), 256, 0, stream>>>(xbf, Wihbf, biasp, xqd);
  lstm_mfma<<<16, 512, 0, stream>>>(xqd, whhp, hf, hb);
  em_kernel<<<64, 256, 0, stream>>>(hf, hb, Wp, bp, em);
  crf_kernel<<<32, 64, 0, stream>>>(em, tags, mask, trans, start_t, end_t, nllb);
  nll_reduce_kernel<<<1, 64, 0, stream>>>(nllb, out);
}